// Round 7
// baseline (263.420 us; speedup 1.0000x reference)
//
#include <hip/hip_runtime.h>

// make_blocks: out[b,p,a,c,:] = concat(seq1M[b, r0+c, :], seq2M[b, c0+a, :], geo[b,p,a,c])
// B=64, L=2048, D=60, P=16, PS=30 -> out [64,16,30,30,121] fp32 (446 MB).
//
// R7: FILL-CLONE global-gather. No LDS, no barriers, no block<->chunk binding.
// Grid-stride loop over output float4s: the whole chip advances ONE dense ~8MB
// write front (like the 6.9 TB/s fillBuffer), instead of 1024-2048 private
// per-block streams (all prior kernels, all stuck at ~4.5 TB/s).
// Sources are gathered directly from global: each seq row is re-read ~30x by
// temporally-adjacent waves -> L2/L3 hits; in-row reads are contiguous.

typedef float f32x4   __attribute__((ext_vector_type(4)));
typedef float f32x4_u __attribute__((ext_vector_type(4), aligned(4)));  // 4B-aligned vec load

constexpr int B_ = 64, L_ = 2048, D_ = 60, P_ = 16, PS_ = 30;
constexpr unsigned KOUT  = 121;
constexpr unsigned ROWF  = 3630;     // PS*KOUT floats per 'a' row
constexpr unsigned CHUNK = 108900;   // PS*PS*KOUT floats per (b,p)
constexpr unsigned NF    = 111513600u;  // total output floats
constexpr unsigned NF4   = NF / 4;      // 27,878,400 float4s

constexpr int NT   = 256;
constexpr int NBLK = 2048;           // 8 blocks/CU, grid-stride

__global__ __launch_bounds__(NT) void make_blocks_38860864094557_kernel(
    const float* __restrict__ s1, const float* __restrict__ s2,
    const float* __restrict__ gg, const int* __restrict__ patches,
    float* __restrict__ out)
{
    const unsigned stride = (unsigned)NBLK * NT;
    for (unsigned i4 = blockIdx.x * NT + threadIdx.x; i4 < NF4; i4 += stride) {
        const unsigned t  = 4u * i4;            // flat float index (< 2^27)
        const unsigned bp = t / CHUNK;          // magic-mul divs
        const unsigned u  = t - bp * CHUNK;
        const unsigned a  = u / ROWF;
        const unsigned r  = u - a * ROWF;
        const unsigned c  = r / KOUT;
        const unsigned k  = r - c * KOUT;
        const unsigned b  = bp >> 4;            // bp / P_

        f32x4 v;
        if (k <= 56u) {
            // all 4 floats in rows-class: seq1[b, r0+c, k..k+3] (contiguous)
            const int r0 = patches[2u * bp];
            v = *reinterpret_cast<const f32x4_u*>(
                    s1 + (size_t)(b * L_ + r0 + c) * D_ + k);
        } else if (k >= 60u && k <= 116u) {
            // all 4 floats in cols-class: seq2[b, c0+a, k-60..k-57]
            const int c0 = patches[2u * bp + 1u];
            v = *reinterpret_cast<const f32x4_u*>(
                    s2 + (size_t)(b * L_ + c0 + a) * D_ + (k - 60u));
        } else {
            // boundary float4 (~7%): per-component with carry. Chunk-crossing
            // carry never occurs (every chunk's last f4 ends exactly at k=120).
#pragma unroll
            for (int j = 0; j < 4; ++j) {
                unsigned kk = k + (unsigned)j, cc = c, aa = a;
                if (kk >= 121u) { kk -= 121u; ++cc; }
                if (cc >= 30u)  { cc = 0u;    ++aa; }
                float val;
                if (kk < 60u) {
                    const int r0 = patches[2u * bp];
                    val = s1[(size_t)(b * L_ + r0 + cc) * D_ + kk];
                } else if (kk < 120u) {
                    const int c0 = patches[2u * bp + 1u];
                    val = s2[(size_t)(b * L_ + c0 + aa) * D_ + (kk - 60u)];
                } else {
                    val = gg[(size_t)bp * 900u + aa * 30u + cc];
                }
                v[j] = val;
            }
        }
        *reinterpret_cast<f32x4*>(out + t) = v;   // dense chip-wide front
    }
}

extern "C" void kernel_launch(void* const* d_in, const int* in_sizes, int n_in,
                              void* d_out, int out_size, void* d_ws, size_t ws_size,
                              hipStream_t stream) {
    const float* seq1    = (const float*)d_in[0];
    const float* seq2    = (const float*)d_in[1];
    const float* geo     = (const float*)d_in[2];
    const int*   patches = (const int*)d_in[3];
    float*       out     = (float*)d_out;

    make_blocks_38860864094557_kernel<<<NBLK, NT, 0, stream>>>(seq1, seq2, geo, patches, out);
}

// Round 8
// 150.031 us; speedup vs baseline: 1.7558x; 1.7558x over previous
//
#include <hip/hip_runtime.h>

// make_blocks: out[b,p,a,c,:] = concat(seq1M[b, r0+c, :], seq2M[b, c0+a, :], geo[b,p,a,c])
// B=64, L=2048, D=60, P=16, PS=30 -> out [64,16,30,30,121] fp32 (446 MB).
//
// R8: WAVE-PER-ROW-PAIR with per-XCD dense write fronts.
//   - Work unit: one output row-PAIR = 242 floats = 968 contiguous bytes.
//     450 pairs per (b,p) chunk exactly (no pair crosses a chunk).
//   - Lane roles are compile-time constants:
//       lanes  0-14 : row0 float4 j=lane   <- seq1 row (240B contiguous, 16B-aligned)
//       lanes 15-29 : row0 float4 j=lane   <- seq2 row (240B contiguous)
//       lane  30    : row0 geo scalar (k=120)
//       lanes 32-61 : row1, same pattern; lane 62: row1 geo; lanes 31,63 idle
//     -> one masked vec4 load + one masked vec4/dword store per lane per pair;
//        stores from the 64 lanes cover one contiguous 968B span.
//   - XCD x (bid&7, round-robin dispatch) owns pair range [x*57600,(x+1)*57600):
//     its 1024 waves interleave consecutive pairs -> ONE dense sequential write
//     front per XCD (fill-like), and chunk sources are XCD-L2-resident
//     (ranges align to whole chunks: 57600/450 = 128 chunks).

typedef float f32x4_u __attribute__((ext_vector_type(4), aligned(4)));

constexpr int B_ = 64, L_ = 2048, D_ = 60, P_ = 16, PS_ = 30;
constexpr int NT   = 256;
constexpr int NBLK = 2048;                        // all-resident, 8 blocks/CU
constexpr int PAIRS         = (B_ * P_ * PS_ * PS_) / 2;  // 460800
constexpr int XCDS          = 8;
constexpr int PAIRS_PER_XCD = PAIRS / XCDS;       // 57600
constexpr int WAVES_PER_XCD = (NBLK / XCDS) * (NT / 64);  // 1024

__global__ __launch_bounds__(NT) void make_blocks_38860864094557_kernel(
    const float* __restrict__ s1, const float* __restrict__ s2,
    const float* __restrict__ gg, const int* __restrict__ patches,
    float* __restrict__ out)
{
    const int lane = threadIdx.x & 63;
    const int wid  = threadIdx.x >> 6;
    const int bid  = blockIdx.x;
    const int xcd  = bid & (XCDS - 1);
    const int lwav = (bid >> 3) * (NT / 64) + wid;          // 0..1023 within XCD

    // Compile-time-ish lane constants.
    const int  rsel  = lane >> 5;          // 0: row0, 1: row1
    const int  j     = lane & 31;          // slot within row
    const bool isf4  = (j < 30);
    const bool isgeo = (j == 30);
    const bool cls1  = (j < 15);           // seq1 vs seq2 span
    const int  offin = ((j < 15) ? j : j - 15) * 16;         // bytes into 240B run
    const int  outof = rsel * 484 + (isgeo ? 480 : j * 16);  // bytes into 968B pair

    const int mEnd = (xcd + 1) * PAIRS_PER_XCD;

#pragma unroll 2
    for (int m = xcd * PAIRS_PER_XCD + lwav; m < mEnd; m += WAVES_PER_XCD) {
        const unsigned bp = (unsigned)m / 450u;     // magic-mul div
        const unsigned u2 = (unsigned)m - bp * 450u;
        const unsigned rr = 2u * u2;                // row index in chunk [0,900)
        const unsigned a0 = rr / 30u;               // magic-mul div
        const unsigned c0 = rr - a0 * 30u;
        unsigned c1 = c0 + 1u, a1 = a0;
        if (c1 == 30u) { c1 = 0u; ++a1; }           // row1 never leaves the chunk
        const unsigned b = bp >> 4;                 // bp / P_

        const int r0p = patches[2u * bp];
        const int c0p = patches[2u * bp + 1u];

        const float* s1b = s1 + (size_t)b * (L_ * D_) + (size_t)r0p * D_;
        const float* s2b = s2 + (size_t)b * (L_ * D_) + (size_t)c0p * D_;
        const float* gb  = gg + (size_t)bp * 900u;

        const char* s1r0 = (const char*)(s1b + c0 * D_);
        const char* s1r1 = (const char*)(s1b + c1 * D_);
        const char* s2r0 = (const char*)(s2b + a0 * D_);
        const char* s2r1 = (const char*)(s2b + a1 * D_);
        const char* g0   = (const char*)(gb + a0 * 30u + c0);
        const char* g1   = (const char*)(gb + a1 * 30u + c1);

        const char* base0 = isgeo ? g0 : (cls1 ? s1r0 : s2r0);
        const char* base1 = isgeo ? g1 : (cls1 ? s1r1 : s2r1);
        const char* src   = (rsel ? base1 : base0) + (isf4 ? offin : 0);
        char*       dst   = (char*)out + (size_t)m * 968u + outof;

        if (isf4) {
            f32x4_u v = *reinterpret_cast<const f32x4_u*>(src);
            *reinterpret_cast<f32x4_u*>(dst) = v;
        } else if (isgeo) {
            float v = *reinterpret_cast<const float*>(src);
            *reinterpret_cast<float*>(dst) = v;
        }
    }
}

extern "C" void kernel_launch(void* const* d_in, const int* in_sizes, int n_in,
                              void* d_out, int out_size, void* d_ws, size_t ws_size,
                              hipStream_t stream) {
    const float* seq1    = (const float*)d_in[0];
    const float* seq2    = (const float*)d_in[1];
    const float* geo     = (const float*)d_in[2];
    const int*   patches = (const int*)d_in[3];
    float*       out     = (float*)d_out;

    make_blocks_38860864094557_kernel<<<NBLK, NT, 0, stream>>>(seq1, seq2, geo, patches, out);
}

// Round 9
// 115.546 us; speedup vs baseline: 2.2798x; 1.2985x over previous
//
#include <hip/hip_runtime.h>

// make_blocks: out[b,p,a,c,:] = concat(seq1M[b, r0+c, :], seq2M[b, c0+a, :], geo[b,p,a,c])
// B=64, L=2048, D=60, P=16, PS=30 -> out [64,16,30,30,121] fp32 (446 MB).
//
// R9: TWO-PHASE read/write separation.
//   Phase A: gather each chunk's sources (rows 1800 | cols 1800 | geo 900 floats)
//            into a DENSE 18KB slab in d_ws (18.4 MB total). All scattered,
//            patch-driven HBM reads happen here, isolated from the write stream.
//   Phase B: R1 (best known, 106.8us) with staging from the dense ws slab —
//            one contiguous 1125-float4 span per chunk, mostly MALL-hits.
//   Theory under test: scattered reads interleaved with the 446MB write stream
//   are the ~33us interference term pinning all prior kernels at ~4.5 TB/s.

constexpr int B_    = 64;
constexpr int L_    = 2048;
constexpr int D_    = 60;
constexpr int P_    = 16;
constexpr int PS_   = 30;
constexpr int KOUT  = 2 * D_ + 1;        // 121
constexpr int ROWLEN = PS_ * KOUT;       // 3630 floats per 'a' row
constexpr int CHUNK  = PS_ * PS_ * KOUT; // 108900 floats per (b,p)
constexpr int NV4    = CHUNK / 4;        // 27225 float4 per (b,p)
constexpr int SPLIT  = 2;                // blocks per (b,p) in phase B
constexpr int NT     = 256;

constexpr int WSF    = 4500;             // ws floats per chunk: 1800|1800|900
constexpr int WSF4   = WSF / 4;          // 1125 float4
constexpr int NCHUNK = B_ * P_;          // 1024

// ---------------- Phase A: dense gather into ws ----------------
__global__ __launch_bounds__(NT) void gather_ws_kernel(
    const float* __restrict__ seq1, const float* __restrict__ seq2,
    const float* __restrict__ geo,  const int* __restrict__ patches,
    float* __restrict__ ws)
{
    const int bp = blockIdx.x;
    const int b  = bp / P_;
    const int r0 = patches[bp * 2 + 0];
    const int c0 = patches[bp * 2 + 1];

    const float4* rsrc = reinterpret_cast<const float4*>(seq1 + ((size_t)b * L_ + r0) * D_);
    const float4* csrc = reinterpret_cast<const float4*>(seq2 + ((size_t)b * L_ + c0) * D_);
    const float4* gsrc = reinterpret_cast<const float4*>(geo  + (size_t)bp * (PS_ * PS_));
    float4*       wdst = reinterpret_cast<float4*>(ws + (size_t)bp * WSF);

    for (int i = threadIdx.x; i < PS_ * D_ / 4; i += NT) {   // 450 f4 each
        wdst[i]       = rsrc[i];
        wdst[450 + i] = csrc[i];
    }
    for (int i = threadIdx.x; i < PS_ * PS_ / 4; i += NT) {  // 225 f4
        wdst[900 + i] = gsrc[i];
    }
}

// ---------------- Phase B: R1 sweep, staging from dense ws ----------------
__global__ __launch_bounds__(NT) void make_blocks_38860864094557_kernel(
    const float* __restrict__ ws, float* __restrict__ out)
{
    __shared__ float sh[WSF];  // [0,1800) rows | [1800,3600) cols | [3600,4500) geo

    const int bid = blockIdx.x;
    const int bp  = bid / SPLIT;
    const int s   = bid % SPLIT;

    const float4* wsrc = reinterpret_cast<const float4*>(ws + (size_t)bp * WSF);
    for (int i = threadIdx.x; i < WSF4; i += NT) {           // 1125 f4, contiguous
        reinterpret_cast<float4*>(sh)[i] = wsrc[i];
    }
    __syncthreads();

    const float* sh_rows = sh;
    const float* sh_cols = sh + 1800;
    const float* sh_geo  = sh + 3600;

    float4* dst = reinterpret_cast<float4*>(out + (size_t)bp * CHUNK);
    const int lo = (NV4 * s) / SPLIT;
    const int hi = (NV4 * (s + 1)) / SPLIT;

    for (int i = lo + (int)threadIdx.x; i < hi; i += NT) {
        const unsigned t = 4u * (unsigned)i;
        float4 v;
        float* vp = reinterpret_cast<float*>(&v);
#pragma unroll
        for (int j = 0; j < 4; ++j) {
            const unsigned tj = t + j;
            const unsigned a  = tj / ROWLEN;          // magic-mul div by 3630
            const unsigned r  = tj - a * ROWLEN;
            const unsigned c  = r / KOUT;             // magic-mul div by 121
            const unsigned k  = r - c * KOUT;
            float val;
            if (k < D_)            val = sh_rows[c * D_ + k];
            else if (k < 2 * D_)   val = sh_cols[a * D_ + (k - D_)];
            else                   val = sh_geo[a * PS_ + c];
            vp[j] = val;
        }
        dst[i] = v;  // coalesced 16B stores, contiguous half-chunk per block
    }
}

extern "C" void kernel_launch(void* const* d_in, const int* in_sizes, int n_in,
                              void* d_out, int out_size, void* d_ws, size_t ws_size,
                              hipStream_t stream) {
    const float* seq1    = (const float*)d_in[0];
    const float* seq2    = (const float*)d_in[1];
    const float* geo     = (const float*)d_in[2];
    const int*   patches = (const int*)d_in[3];
    float*       out     = (float*)d_out;
    float*       ws      = (float*)d_ws;   // needs 18.4 MB

    gather_ws_kernel<<<NCHUNK, NT, 0, stream>>>(seq1, seq2, geo, patches, ws);
    make_blocks_38860864094557_kernel<<<NCHUNK * SPLIT, NT, 0, stream>>>(ws, out);
}